// Round 7
// baseline (202.716 us; speedup 1.0000x reference)
//
#include <hip/hip_runtime.h>

// filtfilt (4th-order IIR, 5-tap FIR) over 512 independent sequences of 48000.
// V9b: V9 (24-sample chunks, ~1.05M threads = 2 resident generations to break
// grid-wide lockstep) with the load-base bug fixed. V9 loaded from float
// 24gc-4, dropping the -15 pad shift (padded p maps to x[p-15]); every thread
// read padded p+15 -> absmax 3.3. The exact window x[24gc-19, 24gc+9) is not
// 16B-aligned (24gc-19 === 1 mod 4), so load 8 float4 from float 24gc-20
// (= 24gc-5-15, float4 index 6gc-5); flat element e holds padded p = 24gc-5+e,
// identical extraction offsets to the verified V8 code (A[n]=flat(n+5),
// history at flat 1..4). All else unchanged from V9: 512-thr blocks, 4-chunk
// halo/side, 504 useful chunks/block, grid 2048, 3-term truncated prefix
// (M24,M48,M72; dropped ||M^96||~1e-10), aligned 12-float4... 6-float4 stores.

#define T48 48000
#define TP0 48030      // padded true length (48000 + 2*15)
#define LCH 24
#define UPB 504        // useful chunks per block

// lgkmcnt(0) + raw barrier: orders LDS ops across waves WITHOUT draining vmcnt.
#define BAR_LDS() do { \
  asm volatile("s_waitcnt lgkmcnt(0)" ::: "memory"); \
  __builtin_amdgcn_s_barrier(); \
} while (0)

__device__ __forceinline__ float fget(const float4& v, int e) {
  switch (e & 3) { case 0: return v.x; case 1: return v.y; case 2: return v.z; default: return v.w; }
}

// t += M * q, M a row-major 4x4 in LDS
#define MAPPLY(t, M, q) do { \
  (t).x += (M)[0]*(q).x  + (M)[1]*(q).y  + (M)[2]*(q).z  + (M)[3]*(q).w; \
  (t).y += (M)[4]*(q).x  + (M)[5]*(q).y  + (M)[6]*(q).z  + (M)[7]*(q).w; \
  (t).z += (M)[8]*(q).x  + (M)[9]*(q).y  + (M)[10]*(q).z + (M)[11]*(q).w; \
  (t).w += (M)[12]*(q).x + (M)[13]*(q).y + (M)[14]*(q).z + (M)[15]*(q).w; \
} while (0)

__global__ __launch_bounds__(512, 4) void filtfilt_k(
    const float* __restrict__ x, const float* __restrict__ bco,
    const float* __restrict__ aco, float* __restrict__ out)
{
  // Region plan (float4 idx): v [0,512) | heads [512,1024) | bv [1024,1536)
  // store-exchange reuses [0,2048) after B4.
  __shared__ __align__(16) float4 S[2048];
  __shared__ float P[3][16];              // P[k] = M24^(k+1), row-major 4x4

  const int t   = threadIdx.x;
  const int seq = blockIdx.x >> 2;
  const int b   = blockIdx.x & 3;
  const int gc  = UPB*b - 4 + t;          // global chunk; t<4 left halo, t>=508 right halo
  const float* __restrict__ xs = x + (size_t)seq * T48;
  const float4* __restrict__ xs4 = reinterpret_cast<const float4*>(xs);
  float* __restrict__ os = out + (size_t)seq * T48;
  float4* __restrict__ os4 = reinterpret_cast<float4*>(os);

  const float inva0 = 1.f / aco[0];
  const float b0 = bco[0]*inva0, b1 = bco[1]*inva0, b2 = bco[2]*inva0,
              b3 = bco[3]*inva0, b4 = bco[4]*inva0;
  const float na1 = -aco[1]*inva0, na2 = -aco[2]*inva0,
              na3 = -aco[3]*inva0, na4 = -aco[4]*inva0;

  // ---------- direct input loads: 8 float4 from float4 idx 6gc-5
  // (float 24gc-20 = 24gc-5-15). Flat element e holds padded p = 24gc-5+e
  // with value x[p-15] = x[24gc-20+e]. Clamped; boundary fixups below.
  float4 F[8];
  const int fb = 6*gc - 5;
#pragma unroll
  for (int k = 0; k < 8; k++) {
    int m = min(max(fb + k, 0), 11999);
    F[k] = xs4[m];
  }

  // ---------- prologue (wave 0): M24 via impulse chains; M48 = M24^2; M72 = M48*M24
  if (t < 64) {
    const int i = (t >> 2) & 3, j = t & 3;
    float r1 = (j==0)?1.f:0.f, r2 = (j==1)?1.f:0.f,
          r3 = (j==2)?1.f:0.f, r4 = (j==3)?1.f:0.f;
#pragma unroll
    for (int n = 0; n < LCH; n++) {
      float h = fmaf(na1, r1, fmaf(na2, r2, fmaf(na3, r3, na4 * r4)));
      r4 = r3; r3 = r2; r2 = r1; r1 = h;
    }
    float c0 = __shfl(r1, j), c1 = __shfl(r2, j),
          c2 = __shfl(r3, j), c3 = __shfl(r4, j);
    float Pv = (i==0)?c0 : (i==1)?c1 : (i==2)?c2 : c3;   // M24 [i][j]
    if (t < 16) P[0][t] = Pv;
    const float P0v = Pv;
    {  // M48 = M24^2
      float rA0 = __shfl(Pv, i*4+0), rA1 = __shfl(Pv, i*4+1),
            rA2 = __shfl(Pv, i*4+2), rA3 = __shfl(Pv, i*4+3);
      float cB0 = __shfl(Pv, 0*4+j), cB1 = __shfl(Pv, 1*4+j),
            cB2 = __shfl(Pv, 2*4+j), cB3 = __shfl(Pv, 3*4+j);
      Pv = rA0*cB0 + rA1*cB1 + rA2*cB2 + rA3*cB3;
    }
    if (t < 16) P[1][t] = Pv;
    {  // M72 = M48 * M24
      float rA0 = __shfl(Pv, i*4+0), rA1 = __shfl(Pv, i*4+1),
            rA2 = __shfl(Pv, i*4+2), rA3 = __shfl(Pv, i*4+3);
      float cB0 = __shfl(P0v, 0*4+j), cB1 = __shfl(P0v, 1*4+j),
            cB2 = __shfl(P0v, 2*4+j), cB3 = __shfl(P0v, 3*4+j);
      Pv = rA0*cB0 + rA1*cB1 + rA2*cB2 + rA3*cB3;
    }
    if (t < 16) P[2][t] = Pv;
  }

  // ---------- extraction: A[n] = flat(n+5) (padded p = 24gc+n);
  // history w4..w1 = flat 1..4 (padded p = 24gc-4 .. 24gc-1)
  float w4v = F[0].y, w3v = F[0].z, w2v = F[0].w, w1v = F[1].x;
  float A[LCH];
#pragma unroll
  for (int n = 0; n < LCH; n++) A[n] = fget(F[(n + 5) >> 2], (n + 5) & 3);

  // ---------- boundary fixups
  if (gc < 0) {                 // pre-sequence halo: exact zero state
    w4v = 0.f; w3v = 0.f; w2v = 0.f; w1v = 0.f;
#pragma unroll
    for (int n = 0; n < LCH; n++) A[n] = 0.f;
  } else if (gc == 0) {         // left odd-reflection, zero history
    float x0d = 2.f * xs[0];
    w4v = 0.f; w3v = 0.f; w2v = 0.f; w1v = 0.f;
#pragma unroll
    for (int n = 0; n < 15; n++) A[n] = x0d - xs[14 - n];
  }
  if (gc >= 2000) {             // right odd-reflection + zero past TP0
    float xld = 2.f * xs[T48 - 1];
#define RFIX(p, var) do { int _p = (p); \
    if (_p >= 48015) var = (_p < TP0) ? (xld - xs[96012 - _p]) : 0.f; } while (0)
    RFIX(24*gc - 4, w4v); RFIX(24*gc - 3, w3v);
    RFIX(24*gc - 2, w2v); RFIX(24*gc - 1, w1v);
#pragma unroll
    for (int n = 0; n < LCH; n++) {
      int p = 24*gc + n;
      if (p >= 48015) A[n] = (p < TP0) ? (xld - xs[96012 - p]) : 0.f;
    }
#undef RFIX
  }

  // ---------- forward phase 1 (in place, zero-state)
  float r1 = 0.f, r2 = 0.f, r3 = 0.f, r4 = 0.f;
#pragma unroll
  for (int n = 0; n < LCH; n++) {
    float xv = A[n];
    float f = fmaf(b0,xv, fmaf(b1,w1v, fmaf(b2,w2v, fmaf(b3,w3v, b4*w4v))));
    w4v = w3v; w3v = w2v; w2v = w1v; w1v = xv;
    float u = fmaf(na4, r4, f);
    u = fmaf(na3, r3, u); u = fmaf(na2, r2, u); u = fmaf(na1, r1, u);
    A[n] = u; r4 = r3; r3 = r2; r2 = r1; r1 = u;
  }

  // ---------- forward prefix: 1 LDS round, 3-term pole-decay truncation
  S[t] = make_float4(r1, r2, r3, r4);
  BAR_LDS();                    // B1: publish v (and P)
  float4 sv = make_float4(0.f,0.f,0.f,0.f);
  if (t >= 1) sv = S[t-1];
  if (t >= 2) { float4 q = S[t-2]; MAPPLY(sv, P[0], q); }
  if (t >= 3) { float4 q = S[t-3]; MAPPLY(sv, P[1], q); }
  if (t >= 4) { float4 q = S[t-4]; MAPPLY(sv, P[2], q); }  // dropped ~||M96||~1e-10

  // ---------- forward phase 2: homogeneous correction
  {
    float h1 = sv.x, h2 = sv.y, h3 = sv.z, h4 = sv.w;
#pragma unroll
    for (int n = 0; n < LCH; n++) {
      float h = fmaf(na1, h1, fmaf(na2, h2, fmaf(na3, h3, na4 * h4)));
      A[n] += h;
      h4 = h3; h3 = h2; h2 = h1; h1 = h;
    }
  }
  // exact zero tail past TP0 (backward pass must see y=0 there)
  if (gc >= 2000) {
#pragma unroll
    for (int n = 0; n < LCH; n++) if (24*gc + n >= TP0) A[n] = 0.f;
  }

  // ---------- exchange heads (backward FIR halo)
  S[512 + t] = make_float4(A[0], A[1], A[2], A[3]);
  BAR_LDS();                    // B2
  float h0 = 0.f, h1v = 0.f, h2v = 0.f, h3v = 0.f;
  if (t < 511) { float4 hv = S[512 + t + 1]; h0 = hv.x; h1v = hv.y; h2v = hv.z; h3v = hv.w; }

  // ---------- backward phase 1 (own chunk reversed, in place)
#define YV(i) ((i) < 24 ? A[(i)] : ((i)==24 ? h0 : (i)==25 ? h1v : (i)==26 ? h2v : h3v))
  r1 = 0.f; r2 = 0.f; r3 = 0.f; r4 = 0.f;
#pragma unroll
  for (int m = 0; m < LCH; m++) {
    float g = fmaf(b0, YV(23-m), fmaf(b1, YV(24-m),
              fmaf(b2, YV(25-m), fmaf(b3, YV(26-m), b4 * YV(27-m)))));
    float u = fmaf(na4, r4, g);
    u = fmaf(na3, r3, u); u = fmaf(na2, r2, u); u = fmaf(na1, r1, u);
    r4 = r3; r3 = r2; r2 = r1; r1 = u;
    if      (m == 0) h3v = u;
    else if (m == 1) h2v = u;
    else if (m == 2) h1v = u;
    else if (m == 3) h0  = u;
    else             A[27 - m] = u;
  }
#undef YV
  // forward-ordered y2[j]: j<=19 -> A[j+4]; 20->h0; 21->h1v; 22->h2v; 23->h3v

  // ---------- backward prefix: 1 LDS round, 3-term truncation (rightward)
  S[1024 + t] = make_float4(r1, r2, r3, r4);
  BAR_LDS();                    // B3: publish bv
  float4 ev = make_float4(0.f,0.f,0.f,0.f);
  if (t <= 510) ev = S[1024 + t + 1];
  if (t <= 509) { float4 q = S[1024 + t + 2]; MAPPLY(ev, P[0], q); }
  if (t <= 508) { float4 q = S[1024 + t + 3]; MAPPLY(ev, P[1], q); }
  if (t <= 507) { float4 q = S[1024 + t + 4]; MAPPLY(ev, P[2], q); }
  BAR_LDS();                    // B4: reuse barrier before exchange overwrites S

  // ---------- backward phase 2
  {
    float g1 = ev.x, g2 = ev.y, g3 = ev.z, g4 = ev.w;
#pragma unroll
    for (int m = 0; m < LCH; m++) {
      float h = fmaf(na1, g1, fmaf(na2, g2, fmaf(na3, g3, na4 * g4)));
      if      (m == 0) h3v += h;
      else if (m == 1) h2v += h;
      else if (m == 2) h1v += h;
      else if (m == 3) h0  += h;
      else             A[27 - m] += h;
      g4 = g3; g3 = g2; g2 = g1; g1 = h;
    }
  }

  // ---------- aligned stores with 15-float neighbor exchange
  // out[24gc + j] = y2_gc[j+15] (j<9) | y2_{gc+1}[j-9] (j>=9)
  // publish y2[0..15] = A[4..19]; lane-consecutive layout (conflict-free)
  S[t]        = make_float4(A[4],  A[5],  A[6],  A[7]);
  S[512 + t]  = make_float4(A[8],  A[9],  A[10], A[11]);
  S[1024 + t] = make_float4(A[12], A[13], A[14], A[15]);
  S[1536 + t] = make_float4(A[16], A[17], A[18], A[19]);
  BAR_LDS();                    // B5
  if (t >= 4 && t < 508 && gc <= 1999) {
    float4 N0 = S[t+1], N1 = S[512 + t+1], N2 = S[1024 + t+1], N3 = S[1536 + t+1];
    float4* op = os4 + 6*gc;
    op[0] = make_float4(A[19], A[20], A[21], A[22]);  // j=0..3  (y2[15..18])
    op[1] = make_float4(A[23], h0,    h1v,   h2v);    // j=4..7  (y2[19..22])
    op[2] = make_float4(h3v,   N0.x,  N0.y,  N0.z);   // j=8..11 (y2[23], nbr y2[0..2])
    op[3] = make_float4(N0.w,  N1.x,  N1.y,  N1.z);   // j=12..15
    op[4] = make_float4(N1.w,  N2.x,  N2.y,  N2.z);   // j=16..19
    op[5] = make_float4(N2.w,  N3.x,  N3.y,  N3.z);   // j=20..23
  }
  // stores are fire-and-forget: kernel-end drain
}

extern "C" void kernel_launch(void* const* d_in, const int* in_sizes, int n_in,
                              void* d_out, int out_size, void* d_ws, size_t ws_size,
                              hipStream_t stream) {
  (void)n_in; (void)d_ws; (void)ws_size; (void)out_size;
  const float* x = (const float*)d_in[0];
  const float* b = (const float*)d_in[1];
  const float* a = (const float*)d_in[2];
  float* out = (float*)d_out;
  const int nseq = in_sizes[0] / T48;   // 512
  filtfilt_k<<<dim3(nseq * 4), dim3(512), 0, stream>>>(x, b, a, out);
}